// Round 4
// baseline (554.649 us; speedup 1.0000x reference)
//
#include <hip/hip_runtime.h>
#include <hip/hip_bf16.h>
#include <math.h>

#define BB 32
#define DD 768
#define AL 10
#define NC 150
#define CTX 77
#define TD 512
#define SCALE 0.036084391824351615f  /* 768^-0.5 */
#define CHUNKS 32
#define ROWS_PB 32
#define PS ((size_t)320 * DD)   /* split-K partial slice stride */

// ---------------- fused text prep: mean over ctx + L2 normalize ----------------
__global__ void k_tp(const float* __restrict__ tfeat, float* __restrict__ tfn) {
    int c = blockIdx.x, t = threadIdx.x;  // 150 x 256
    const float* base = tfeat + (size_t)c * CTX * TD;
    float s0 = 0.f, s1 = 0.f;
    #pragma unroll 4
    for (int j = 0; j < CTX; ++j) {
        s0 += base[j * TD + t];
        s1 += base[j * TD + t + 256];
    }
    s0 *= (1.f / CTX); s1 *= (1.f / CTX);
    __shared__ float red[256];
    red[t] = s0 * s0 + s1 * s1;
    __syncthreads();
    for (int o = 128; o > 0; o >>= 1) { if (t < o) red[t] += red[t + o]; __syncthreads(); }
    float rn = rsqrtf(red[0]);
    tfn[c * TD + t] = s0 * rn;
    tfn[c * TD + t + 256] = s1 * rn;
}

// ---------------- temb = relu(tfn @ wt.T + bt) + fused wtext raw-dot atomics ----------------
__global__ void k_temb(const float* __restrict__ tfn, const float* __restrict__ wt,
                       const float* __restrict__ bt, const float* __restrict__ agent,
                       const int* __restrict__ layerp, float* __restrict__ temb,
                       float* __restrict__ wtex_raw) {
    int c = blockIdx.x, dch = blockIdx.y;  // (150,3)
    int t = threadIdx.x, lane = t & 63;
    __shared__ float row[TD];
    __shared__ float wsum[16];
    row[t] = tfn[(size_t)c * TD + t];
    row[t + 256] = tfn[(size_t)c * TD + t + 256];
    if (t < 16) wsum[t] = 0.f;
    __syncthreads();
    int d = dch * 256 + t;
    const float* wr = wt + (size_t)d * TD;
    float acc = bt[d];
    for (int k = 0; k < TD; k += 4) {
        float4 w4 = *reinterpret_cast<const float4*>(wr + k);
        acc += row[k] * w4.x + row[k + 1] * w4.y + row[k + 2] * w4.z + row[k + 3] * w4.w;
    }
    float tv = fmaxf(acc, 0.f);
    temb[(size_t)c * DD + d] = tv;
    const float* ag = agent + (size_t)layerp[0] * AL * DD + d;
    #pragma unroll
    for (int a = 0; a < AL; ++a) {
        float p = tv * ag[(size_t)a * DD];
        #pragma unroll
        for (int o = 1; o < 64; o <<= 1) p += __shfl_xor(p, o);
        if (lane == 0) atomicAdd(&wsum[a], p);
    }
    __syncthreads();
    if (t < AL) atomicAdd(&wtex_raw[c * AL + t], wsum[t]);
}

// ---------------- fused ptext + B10: pooled_text@wm.T + bm + agent : grid (10,3) ----------------
__global__ void k_text2(const float* __restrict__ temb, const float* __restrict__ wtex_raw,
                        const float* __restrict__ wm, const float* __restrict__ bm,
                        const float* __restrict__ agent, const int* __restrict__ layerp,
                        float* __restrict__ B10) {
    int a = blockIdx.x, dch = blockIdx.y;
    int t = threadIdx.x;
    __shared__ float pooled[DD];
    __shared__ float wv[NC];
    __shared__ float red[256];
    float myw = 0.f;
    if (t < NC) { myw = 1.f / (1.f + __expf(-wtex_raw[t * AL + a] * SCALE)); wv[t] = myw; }
    red[t] = myw;
    __syncthreads();
    for (int o = 128; o > 0; o >>= 1) { if (t < o) red[t] += red[t + o]; __syncthreads(); }
    float inv = 1.f / (red[0] + 1e-6f);
    float p0 = 0.f, p1 = 0.f, p2 = 0.f;
    #pragma unroll 2
    for (int c = 0; c < NC; ++c) {
        float wc = wv[c];
        const float* tr = temb + (size_t)c * DD;
        p0 += wc * tr[t]; p1 += wc * tr[t + 256]; p2 += wc * tr[t + 512];
    }
    pooled[t] = p0 * inv; pooled[t + 256] = p1 * inv; pooled[t + 512] = p2 * inv;
    __syncthreads();
    int d = dch * 256 + t;
    const float* wr = wm + (size_t)d * DD;
    float acc = 0.f;
    for (int k = 0; k < DD; k += 4) {
        float4 w4 = *reinterpret_cast<const float4*>(wr + k);
        acc += pooled[k] * w4.x + pooled[k + 1] * w4.y + pooled[k + 2] * w4.z + pooled[k + 3] * w4.w;
    }
    B10[(size_t)a * DD + d] = acc + bm[d] + agent[((size_t)layerp[0] * AL + a) * DD + d];
}

// ---------------- pass 1: phase A dots+sigmoid (shfl), phase B pooling (L2 re-read) ----------------
__global__ __launch_bounds__(256, 4)
void k_pass1(const float* __restrict__ outp, const float* __restrict__ agent,
             const int* __restrict__ layerp, __hip_bfloat16* __restrict__ num_bf,
             float* __restrict__ den_part) {
    int chunk = blockIdx.x, b = blockIdx.y;  // (32,32)
    int tid = threadIdx.x, lane = tid & 63, w = tid >> 6;
    __shared__ float agl[AL * DD];       // 30 KB
    __shared__ float wl[ROWS_PB][AL];
    const float* ab = agent + (size_t)layerp[0] * AL * DD;
    for (int i = tid; i < AL * DD; i += 256) agl[i] = ab[i];
    __syncthreads();
    const float4* agl4 = reinterpret_cast<const float4*>(agl);
    // phase A: wave w does rows [w*8, w*8+8) pairwise
    #pragma unroll
    for (int pr = 0; pr < 4; ++pr) {
        int ra = w * 8 + pr * 2, rb = ra + 1;
        const float* pA = outp + ((size_t)(1 + chunk * ROWS_PB + ra) * BB + b) * DD + lane * 4;
        const float* pB = pA + (size_t)BB * DD;
        float4 xa0 = *(const float4*)(pA);
        float4 xa1 = *(const float4*)(pA + 256);
        float4 xa2 = *(const float4*)(pA + 512);
        float4 xb0 = *(const float4*)(pB);
        float4 xb1 = *(const float4*)(pB + 256);
        float4 xb2 = *(const float4*)(pB + 512);
        #pragma unroll
        for (int a = 0; a < AL; ++a) {
            float4 c0 = agl4[a * 192 + lane];
            float4 c1 = agl4[a * 192 + 64 + lane];
            float4 c2 = agl4[a * 192 + 128 + lane];
            float pa = xa0.x*c0.x + xa0.y*c0.y + xa0.z*c0.z + xa0.w*c0.w
                     + xa1.x*c1.x + xa1.y*c1.y + xa1.z*c1.z + xa1.w*c1.w
                     + xa2.x*c2.x + xa2.y*c2.y + xa2.z*c2.z + xa2.w*c2.w;
            float pb = xb0.x*c0.x + xb0.y*c0.y + xb0.z*c0.z + xb0.w*c0.w
                     + xb1.x*c1.x + xb1.y*c1.y + xb1.z*c1.z + xb1.w*c1.w
                     + xb2.x*c2.x + xb2.y*c2.y + xb2.z*c2.z + xb2.w*c2.w;
            #pragma unroll
            for (int o = 1; o < 64; o <<= 1) { pa += __shfl_xor(pa, o); pb += __shfl_xor(pb, o); }
            if (lane == a) {
                wl[ra][a] = 1.f / (1.f + __expf(-pa * SCALE));
                wl[rb][a] = 1.f / (1.f + __expf(-pb * SCALE));
            }
        }
    }
    __syncthreads();
    // phase B: pooling, x re-read from L2/L3
    float acc0[AL], acc1[AL], acc2[AL];
    #pragma unroll
    for (int a = 0; a < AL; ++a) { acc0[a] = 0.f; acc1[a] = 0.f; acc2[a] = 0.f; }
    #pragma unroll 4
    for (int row = 0; row < ROWS_PB; ++row) {
        const float* fr = outp + ((size_t)(1 + chunk * ROWS_PB + row) * BB + b) * DD;
        float x0 = fr[tid], x1 = fr[tid + 256], x2 = fr[tid + 512];
        #pragma unroll
        for (int a = 0; a < AL; ++a) {
            float wg = wl[row][a];
            acc0[a] += wg * x0; acc1[a] += wg * x1; acc2[a] += wg * x2;
        }
    }
    __hip_bfloat16* np_ = num_bf + ((size_t)b * CHUNKS + chunk) * AL * DD;
    #pragma unroll
    for (int a = 0; a < AL; ++a) {
        np_[a * DD + tid]       = __float2bfloat16(acc0[a]);
        np_[a * DD + tid + 256] = __float2bfloat16(acc1[a]);
        np_[a * DD + tid + 512] = __float2bfloat16(acc2[a]);
    }
    if (tid < AL) {
        float dn = 0.f;
        #pragma unroll
        for (int rw = 0; rw < ROWS_PB; ++rw) dn += wl[rw][tid];
        den_part[((size_t)b * CHUNKS + chunk) * AL + tid] = dn;
    }
}

// ---------------- reduce partials -> pooled_vis ----------------
__global__ void k_poolvis(const __hip_bfloat16* __restrict__ num_bf,
                          const float* __restrict__ den_part, float* __restrict__ pvis) {
    int idx = blockIdx.x;  // 320 = b*10+a
    int a = idx % AL, b = idx / AL;
    int t = threadIdx.x;
    float den = 0.f;
    for (int c = 0; c < CHUNKS; ++c) den += den_part[((size_t)b * CHUNKS + c) * AL + a];
    float inv = 1.f / (den + 1e-6f);
    for (int dd = 0; dd < 3; ++dd) {
        int d = dd * 256 + t;
        float num = 0.f;
        #pragma unroll 4
        for (int c = 0; c < CHUNKS; ++c)
            num += __bfloat162float(num_bf[((size_t)b * CHUNKS + c) * AL * DD + a * DD + d]);
        pvis[((size_t)b * AL + a) * DD + d] = num * inv;
    }
}

// ---------------- split-K GEMM: part[ks][m][n] += A[m,k-slice] @ W[n,k-slice]^T ----------------
__global__ __launch_bounds__(256)
void k_gemmsk(const float* __restrict__ A, const float* __restrict__ W,
              float* __restrict__ part) {
    int n0 = blockIdx.x * 64, m0 = blockIdx.y * 64, k0 = blockIdx.z * 192;
    int tid = threadIdx.x;
    int tx = tid % 16, ty = tid / 16;
    __shared__ float As[64][36];
    __shared__ float Ws[64][36];
    float acc[4][4] = {};
    for (int kk = 0; kk < 192; kk += 32) {
        #pragma unroll
        for (int s = 0; s < 2; ++s) {
            int i = s * 256 + tid;
            int r = i >> 3, c4 = (i & 7) * 4;
            float4 av = *reinterpret_cast<const float4*>(A + (size_t)(m0 + r) * DD + k0 + kk + c4);
            float4 wv = *reinterpret_cast<const float4*>(W + (size_t)(n0 + r) * DD + k0 + kk + c4);
            *reinterpret_cast<float4*>(&As[r][c4]) = av;
            *reinterpret_cast<float4*>(&Ws[r][c4]) = wv;
        }
        __syncthreads();
        #pragma unroll
        for (int k4 = 0; k4 < 32; k4 += 4) {
            float4 a[4], wv[4];
            #pragma unroll
            for (int i = 0; i < 4; ++i) a[i] = *reinterpret_cast<const float4*>(&As[ty * 4 + i][k4]);
            #pragma unroll
            for (int j = 0; j < 4; ++j) wv[j] = *reinterpret_cast<const float4*>(&Ws[tx * 4 + j][k4]);
            #pragma unroll
            for (int i = 0; i < 4; ++i)
                #pragma unroll
                for (int j = 0; j < 4; ++j)
                    acc[i][j] += a[i].x * wv[j].x + a[i].y * wv[j].y
                               + a[i].z * wv[j].z + a[i].w * wv[j].w;
        }
        __syncthreads();
    }
    float* pb = part + (size_t)blockIdx.z * PS;
    #pragma unroll
    for (int i = 0; i < 4; ++i) {
        int m = m0 + ty * 4 + i;
        #pragma unroll
        for (int j = 0; j < 4; ++j)
            pb[(size_t)m * DD + n0 + tx * 4 + j] = acc[i][j];
    }
}

// ---------------- same GEMM but A = sum of 4 split-K slices + kbias (fused reduce) ----------------
__global__ __launch_bounds__(256)
void k_gemmskf(const float* __restrict__ Aparts, const float* __restrict__ kbias,
               const float* __restrict__ W, float* __restrict__ part) {
    int n0 = blockIdx.x * 64, m0 = blockIdx.y * 64, k0 = blockIdx.z * 192;
    int tid = threadIdx.x;
    int tx = tid % 16, ty = tid / 16;
    __shared__ float As[64][36];
    __shared__ float Ws[64][36];
    float acc[4][4] = {};
    for (int kk = 0; kk < 192; kk += 32) {
        #pragma unroll
        for (int s = 0; s < 2; ++s) {
            int i = s * 256 + tid;
            int r = i >> 3, c4 = (i & 7) * 4;
            size_t aoff = (size_t)(m0 + r) * DD + k0 + kk + c4;
            float4 a0 = *reinterpret_cast<const float4*>(Aparts + aoff);
            float4 a1 = *reinterpret_cast<const float4*>(Aparts + PS + aoff);
            float4 a2 = *reinterpret_cast<const float4*>(Aparts + 2 * PS + aoff);
            float4 a3 = *reinterpret_cast<const float4*>(Aparts + 3 * PS + aoff);
            float4 bb = *reinterpret_cast<const float4*>(kbias + k0 + kk + c4);
            float4 av;
            av.x = a0.x + a1.x + a2.x + a3.x + bb.x;
            av.y = a0.y + a1.y + a2.y + a3.y + bb.y;
            av.z = a0.z + a1.z + a2.z + a3.z + bb.z;
            av.w = a0.w + a1.w + a2.w + a3.w + bb.w;
            float4 wv = *reinterpret_cast<const float4*>(W + (size_t)(n0 + r) * DD + k0 + kk + c4);
            *reinterpret_cast<float4*>(&As[r][c4]) = av;
            *reinterpret_cast<float4*>(&Ws[r][c4]) = wv;
        }
        __syncthreads();
        #pragma unroll
        for (int k4 = 0; k4 < 32; k4 += 4) {
            float4 a[4], wv[4];
            #pragma unroll
            for (int i = 0; i < 4; ++i) a[i] = *reinterpret_cast<const float4*>(&As[ty * 4 + i][k4]);
            #pragma unroll
            for (int j = 0; j < 4; ++j) wv[j] = *reinterpret_cast<const float4*>(&Ws[tx * 4 + j][k4]);
            #pragma unroll
            for (int i = 0; i < 4; ++i)
                #pragma unroll
                for (int j = 0; j < 4; ++j)
                    acc[i][j] += a[i].x * wv[j].x + a[i].y * wv[j].y
                               + a[i].z * wv[j].z + a[i].w * wv[j].w;
        }
        __syncthreads();
    }
    float* pb = part + (size_t)blockIdx.z * PS;
    #pragma unroll
    for (int i = 0; i < 4; ++i) {
        int m = m0 + ty * 4 + i;
        #pragma unroll
        for (int j = 0; j < 4; ++j)
            pb[(size_t)m * DD + n0 + tx * 4 + j] = acc[i][j];
    }
}

// ---------------- text attention (q = sum partsA + bm + B10 fused) : grid (10,32) ----------------
__global__ void k_tattn(const float* __restrict__ partsA, const float* __restrict__ bm,
                        const float* __restrict__ B10, const float* __restrict__ temb,
                        float* __restrict__ u) {
    int a = blockIdx.x, b = blockIdx.y;
    int t = threadIdx.x;
    __shared__ float q[DD];
    __shared__ float p[NC];
    __shared__ float red[256];
    const float* pA = partsA + ((size_t)b * AL + a) * DD;
    const float* br = B10 + (size_t)a * DD;
    for (int i = t; i < DD; i += 256)
        q[i] = pA[i] + pA[PS + i] + pA[2 * PS + i] + pA[3 * PS + i] + bm[i] + br[i];
    __syncthreads();
    float myp = -1e30f;
    if (t < NC) {
        const float* tr = temb + (size_t)t * DD;
        float s = 0.f;
        for (int k = 0; k < DD; k += 4) {
            float4 t4 = *reinterpret_cast<const float4*>(tr + k);
            s += q[k] * t4.x + q[k + 1] * t4.y + q[k + 2] * t4.z + q[k + 3] * t4.w;
        }
        myp = s * SCALE;
    }
    red[t] = myp; __syncthreads();
    for (int o = 128; o > 0; o >>= 1) { if (t < o) red[t] = fmaxf(red[t], red[t + o]); __syncthreads(); }
    float mx = red[0]; __syncthreads();
    float e = (t < NC) ? __expf(myp - mx) : 0.f;
    red[t] = e; __syncthreads();
    for (int o = 128; o > 0; o >>= 1) { if (t < o) red[t] += red[t + o]; __syncthreads(); }
    float inv = 1.f / red[0];
    if (t < NC) p[t] = e * inv;
    __syncthreads();
    float u0 = 0.f, u1 = 0.f, u2 = 0.f;
    #pragma unroll 2
    for (int c = 0; c < NC; ++c) {
        const float* tr = temb + (size_t)c * DD;
        float pc = p[c];
        u0 += pc * tr[t]; u1 += pc * tr[t + 256]; u2 += pc * tr[t + 512];
    }
    float* ur = u + ((size_t)b * AL + a) * DD;
    ur[t] = u0; ur[t + 256] = u1; ur[t + 512] = u2;
}

// ---------------- pass 2: fused ag2/v2 split-K reduce + softmax + AV + residual ----------------
__global__ __launch_bounds__(256, 4)
void k_pass2(const float* __restrict__ outp, const float* __restrict__ partsA,
             const float* __restrict__ bm, const float* __restrict__ B10,
             const float* __restrict__ partsC, const float* __restrict__ b2,
             const float* __restrict__ ascale, float* __restrict__ out) {
    int chunk = blockIdx.x, b = blockIdx.y;  // (32,32)
    int tid = threadIdx.x, lane = tid & 63, w = tid >> 6;
    __shared__ float agl[AL * DD];      // 30 KB
    __shared__ float pl[ROWS_PB][AL];
    // vr = v2 rows = sum partsC slices + b2  (30 regs)
    float vr0[AL], vr1[AL], vr2[AL];
    const float* pC = partsC + (size_t)b * AL * DD;
    #pragma unroll
    for (int a = 0; a < AL; ++a) {
        size_t i0 = (size_t)a * DD + tid;
        vr0[a] = pC[i0] + pC[PS + i0] + pC[2 * PS + i0] + pC[3 * PS + i0] + b2[tid];
        size_t i1 = i0 + 256;
        vr1[a] = pC[i1] + pC[PS + i1] + pC[2 * PS + i1] + pC[3 * PS + i1] + b2[tid + 256];
        size_t i2 = i0 + 512;
        vr2[a] = pC[i2] + pC[PS + i2] + pC[2 * PS + i2] + pC[3 * PS + i2] + b2[tid + 512];
    }
    // agl = ag2 rows for this b = sum partsA + bm + B10
    const float* pA = partsA + (size_t)b * AL * DD;
    #pragma unroll
    for (int j = 0; j < 30; ++j) {
        int a = j / 3, d = (j % 3) * 256 + tid;
        int i = a * DD + d;
        agl[i] = pA[i] + pA[PS + i] + pA[2 * PS + i] + pA[3 * PS + i] + bm[d] + B10[i];
    }
    float asc = ascale[0];
    __syncthreads();
    const float4* agl4 = reinterpret_cast<const float4*>(agl);
    // phase A: wave w rows [w*8, w*8+8) pairwise: scores -> softmax -> pl
    #pragma unroll
    for (int pr = 0; pr < 4; ++pr) {
        int ra = w * 8 + pr * 2, rb = ra + 1;
        const float* pAx = outp + ((size_t)(1 + chunk * ROWS_PB + ra) * BB + b) * DD + lane * 4;
        const float* pBx = pAx + (size_t)BB * DD;
        float4 xa0 = *(const float4*)(pAx);
        float4 xa1 = *(const float4*)(pAx + 256);
        float4 xa2 = *(const float4*)(pAx + 512);
        float4 xb0 = *(const float4*)(pBx);
        float4 xb1 = *(const float4*)(pBx + 256);
        float4 xb2 = *(const float4*)(pBx + 512);
        float sA[AL], sB[AL];
        #pragma unroll
        for (int a = 0; a < AL; ++a) {
            float4 c0 = agl4[a * 192 + lane];
            float4 c1 = agl4[a * 192 + 64 + lane];
            float4 c2 = agl4[a * 192 + 128 + lane];
            float pa = xa0.x*c0.x + xa0.y*c0.y + xa0.z*c0.z + xa0.w*c0.w
                     + xa1.x*c1.x + xa1.y*c1.y + xa1.z*c1.z + xa1.w*c1.w
                     + xa2.x*c2.x + xa2.y*c2.y + xa2.z*c2.z + xa2.w*c2.w;
            float pb = xb0.x*c0.x + xb0.y*c0.y + xb0.z*c0.z + xb0.w*c0.w
                     + xb1.x*c1.x + xb1.y*c1.y + xb1.z*c1.z + xb1.w*c1.w
                     + xb2.x*c2.x + xb2.y*c2.y + xb2.z*c2.z + xb2.w*c2.w;
            #pragma unroll
            for (int o = 1; o < 64; o <<= 1) { pa += __shfl_xor(pa, o); pb += __shfl_xor(pb, o); }
            sA[a] = pa * SCALE; sB[a] = pb * SCALE;
        }
        float mA = sA[0], mB = sB[0];
        #pragma unroll
        for (int a = 1; a < AL; ++a) { mA = fmaxf(mA, sA[a]); mB = fmaxf(mB, sB[a]); }
        float ZA = 0.f, ZB = 0.f;
        #pragma unroll
        for (int a = 0; a < AL; ++a) {
            sA[a] = __expf(sA[a] - mA); ZA += sA[a];
            sB[a] = __expf(sB[a] - mB); ZB += sB[a];
        }
        float iA = asc / ZA, iB = asc / ZB;
        #pragma unroll
        for (int a = 0; a < AL; ++a) {
            if (lane == a) { pl[ra][a] = sA[a] * iA; pl[rb][a] = sB[a] * iB; }
        }
    }
    __syncthreads();
    // phase B: AV + residual, x re-read from L2/L3
    #pragma unroll 4
    for (int row = 0; row < ROWS_PB; ++row) {
        const float* fr = outp + ((size_t)(1 + chunk * ROWS_PB + row) * BB + b) * DD;
        float x0 = fr[tid], x1 = fr[tid + 256], x2 = fr[tid + 512];
        float d0 = 0.f, d1 = 0.f, d2 = 0.f;
        #pragma unroll
        for (int a = 0; a < AL; ++a) {
            float pa = pl[row][a];
            d0 += pa * vr0[a]; d1 += pa * vr1[a]; d2 += pa * vr2[a];
        }
        float* orow = out + ((size_t)(1 + chunk * ROWS_PB + row) * BB + b) * DD;
        orow[tid]       = x0 + d0;
        orow[tid + 256] = x1 + d1;
        orow[tid + 512] = x2 + d2;
    }
}

extern "C" void kernel_launch(void* const* d_in, const int* in_sizes, int n_in,
                              void* d_out, int out_size, void* d_ws, size_t ws_size,
                              hipStream_t stream) {
    const float* outp   = (const float*)d_in[0];
    const float* tfeat  = (const float*)d_in[1];
    const float* agent  = (const float*)d_in[2];
    const float* ascale = (const float*)d_in[3];
    const float* w1 = (const float*)d_in[4];
    const float* b1 = (const float*)d_in[5];
    const float* w2 = (const float*)d_in[6];
    const float* b2 = (const float*)d_in[7];
    const float* wm = (const float*)d_in[8];
    const float* bm = (const float*)d_in[9];
    const float* wt = (const float*)d_in[10];
    const float* bt = (const float*)d_in[11];
    const int* layerp = (const int*)d_in[12];
    float* out = (float*)d_out;

    float* ws = (float*)d_ws;
    float* tfn      = ws;                  // 76800
    float* temb     = tfn + 76800;         // 115200
    float* wtex_raw = temb + 115200;       // 1536
    float* B10      = wtex_raw + 1536;     // 7680
    float* pvis     = B10 + 7680;          // 245760
    float* u        = pvis + 245760;       // 245760
    float* den_part = u + 245760;          // 10240
    float* big      = den_part + 10240;    // 3932160 floats (shared region)
    float* partsA = big;
    float* partsB = big + 983040;
    float* partsC = big + 1966080;
    __hip_bfloat16* num_bf = (__hip_bfloat16*)big;  // consumed by k_poolvis before partsA written

    hipMemsetAsync(wtex_raw, 0, NC * AL * sizeof(float), stream);
    // cls token row
    hipMemcpyAsync(out, outp, (size_t)BB * DD * sizeof(float),
                   hipMemcpyDeviceToDevice, stream);

    k_pass1<<<dim3(CHUNKS, BB), 256, 0, stream>>>(outp, agent, layerp, num_bf, den_part);
    k_tp<<<NC, 256, 0, stream>>>(tfeat, tfn);
    k_temb<<<dim3(NC, 3), 256, 0, stream>>>(tfn, wt, bt, agent, layerp, temb, wtex_raw);
    k_text2<<<dim3(AL, 3), 256, 0, stream>>>(temb, wtex_raw, wm, bm, agent, layerp, B10);
    k_poolvis<<<BB * AL, 256, 0, stream>>>(num_bf, den_part, pvis);
    // partsA = split-K(pvis @ wm.T); ag2 = sum(partsA)+bm+B10 computed by consumers
    k_gemmsk<<<dim3(12, 5, 4), 256, 0, stream>>>(pvis, wm, partsA);
    k_tattn<<<dim3(AL, BB), 256, 0, stream>>>(partsA, bm, B10, temb, u);
    // partsB = split-K(u @ w1.T); v = sum(partsB)+b1 consumed by next GEMM's A-load
    k_gemmsk<<<dim3(12, 5, 4), 256, 0, stream>>>(u, w1, partsB);
    // partsC = split-K(v @ w2.T); v2 = sum(partsC)+b2 consumed by pass2
    k_gemmskf<<<dim3(12, 5, 4), 256, 0, stream>>>(partsB, b1, w2, partsC);
    k_pass2<<<dim3(CHUNKS, BB), 256, 0, stream>>>(outp, partsA, bm, B10, partsC, b2, ascale, out);
}